// Round 5
// baseline (2127.442 us; speedup 1.0000x reference)
//
#include <hip/hip_runtime.h>
#include <hip/hip_bf16.h>
#include <stdint.h>

// Persistent-RNN, R9: intra-XCD L2-scope state exchange + IC mirror for liveness.
//  - 128 blocks x 512 threads (8 waves). 8 batch-groups x 16 col-blocks.
//  - Block (g,m): g = blockIdx&7 (group==XCD under round-robin dispatch -- PROVEN
//    by R8's 6.6x FETCH_SIZE drop from x-read L2 dedup), m = blockIdx>>3.
//  - R8 -> R9:
//      * Producer stores the tagged state TWICE: (a) plain global_store (no sc
//        bits) into the L2 buffer -- L1 is write-through, so this lands in the
//        producer XCD's L2, which co-resident consumers share; (b) sc1 store
//        into a separate MIRROR buffer (IC truth). Store (a) makes the
//        store->detect hop an L2 round trip (~200-300cy) instead of IC (~900cy).
//      * Consumer: sc0 sweeps on the L2 buffer (consumer's failing polls cache
//        the line in the SAME L2 the producer updates -> detection at L2 hit
//        latency); every 8th failing sweep, one sc1 sweep on the mirror
//        (liveness if any pair lands cross-XCD). Whichever sweep passes IS the
//        state load; sweeps are individually self-consistent.
//      * Readout reads the MIRROR (sc1-written -> unconditionally visible after
//        kernel completion; no reliance on end-of-kernel L2 flush).
//  - Tag protocol unchanged: u32 = (bf16hi<<16)|(bf16lo&~1|parity); all 32 tags
//    must equal (t>>1)&1. Stale lines (step t-2, same buffer) carry the
//    OPPOSITE tag -> cannot false-pass. Per-dword tags cover torn lines.
//  - WAR safety: as R5 -- any fresh word of producer B implies B passed its
//    step-(t-1) block barrier, implying all B's step-(t-1) state reads retired.

#define TSTEPS 512
#define BATCH  128
#define NI     256
#define NH     1024
#define NO     128
#define NBLK   128
#define NTHR   512
#define NWAVE  8
#define BG     16
#define COLS   64
#define SPBUF  ((size_t)BATCH * NH)          // u32s per state buffer (2^17)

typedef __attribute__((ext_vector_type(8))) short s16x8;
typedef __attribute__((ext_vector_type(4))) float f32x4;
typedef __attribute__((ext_vector_type(4))) unsigned u32x4;
typedef unsigned long long ull;

__device__ __forceinline__ unsigned short f2bf_rne(float f) {
  unsigned u = __builtin_bit_cast(unsigned, f);
  unsigned r = u + 0x7fffu + ((u >> 16) & 1u);
  return (unsigned short)(r >> 16);
}
__device__ __forceinline__ float bf2f(unsigned short h) {
  unsigned u = ((unsigned)h) << 16;
  return __builtin_bit_cast(float, u);
}
__device__ __forceinline__ void split_bf(float v, short &hi, short &lo) {
  unsigned short h = f2bf_rne(v);
  hi = (short)h;
  lo = (short)f2bf_rne(v - bf2f(h));
}
__device__ __forceinline__ f32x4 mfma16(s16x8 a, s16x8 b, f32x4 c) {
  return __builtin_amdgcn_mfma_f32_16x16x32_bf16(a, b, c, 0, 0, 0);
}
__device__ __forceinline__ float fast_tanh(float a) {
  float cl = fminf(fmaxf(a, -15.f), 15.f);
  float e  = __expf(2.f * cl);
  return (e - 1.f) / (e + 1.f);
}

// state u32 index: [g 0..8)[w 0..8)[r 0..16)[k_local 0..128)
//   global K = w*128 + k_local ; batch row = g*16 + r
#define SIDX(g, w, r, k) ((((size_t)(g) * NWAVE + (w)) * BG + (r)) * 128 + (k))

__global__ __launch_bounds__(NTHR, 2)
void rnn_persistent(const float* __restrict__ x,
                    const float* __restrict__ W_ih,
                    const float* __restrict__ W_hh,
                    const float* __restrict__ b_ih,
                    const float* __restrict__ b_hh,
                    unsigned*    __restrict__ SP)    // [4][128][1024]: L2buf0,L2buf1,MIR0,MIR1
{
  const int tid  = threadIdx.x;
  const int wave = tid >> 6;
  const int lane = tid & 63;
  const int lr   = lane & 15;
  const int lq   = lane >> 4;
  const int g    = blockIdx.x & 7;     // group == chain == XCD (round-robin, proven R8)
  const int m    = blockIdx.x >> 3;    // 16 col-blocks per group
  const int row0 = g * BG;
  const int h0   = m * COLS;
  const int kq0  = wave * 128;         // this wave's hidden-K slice
  const int iq0  = wave * 32;          // this wave's input-K slice

  __shared__ float red[2][NWAVE][1024];

  // ---- persistent W_hh B-fragments: [n-tile 0..3][kb 0..3], hi/lo ----
  s16x8 whh_hi[4][4], whh_lo[4][4];
  #pragma unroll
  for (int nt = 0; nt < 4; ++nt) {
    const int h = h0 + nt * 16 + lr;
    #pragma unroll
    for (int kb = 0; kb < 4; ++kb) {
      const float* p = W_hh + (size_t)h * NH + kq0 + kb * 32 + lq * 8;
      s16x8 hi, lo;
      #pragma unroll
      for (int j = 0; j < 8; ++j) { short a, b; split_bf(p[j], a, b); hi[j] = a; lo[j] = b; }
      whh_hi[nt][kb] = hi; whh_lo[nt][kb] = lo;
    }
  }
  // ---- persistent W_ih B-fragments: [n-tile 0..3], single 32-wide kb ----
  s16x8 wih_hi[4], wih_lo[4];
  #pragma unroll
  for (int nt = 0; nt < 4; ++nt) {
    const int h = h0 + nt * 16 + lr;
    const float* p = W_ih + (size_t)h * NI + iq0 + lq * 8;
    s16x8 hi, lo;
    #pragma unroll
    for (int j = 0; j < 8; ++j) { short a, b; split_bf(p[j], a, b); hi[j] = a; lo[j] = b; }
    wih_hi[nt] = hi; wih_lo[nt] = lo;
  }

  // epilogue ownership: thread -> row tid>>5, cols 2*(tid&31), +1
  const int er = tid >> 5;
  const int ec = (tid & 31) * 2;
  const float bias0 = b_ih[h0 + ec]     + b_hh[h0 + ec];
  const float bias1 = b_ih[h0 + ec + 1] + b_hh[h0 + ec + 1];
  const int wsl = m >> 1;              // wave-slice this block's cols land in
  const int klo = (m & 1) * 64 + ec;   // k_local of this thread's pair

  unsigned* lb0 = SP;                  // L2-scope double buffer
  unsigned* lb1 = SP + SPBUF;
  unsigned* mr0 = SP + 2 * SPBUF;      // IC mirror double buffer
  unsigned* mr1 = SP + 3 * SPBUF;

  // x prefetch registers (step 0)
  float xf[8];
  {
    const float* xp = x + (size_t)(row0 + lr) * NI + iq0 + lq * 8;
    #pragma unroll
    for (int j = 0; j < 8; ++j) xf[j] = xp[j];
  }

  // consumer poll bases: this wave's contiguous slice, per-lane fragment offset
  const size_t soff = SIDX(g, wave, lr, lq * 8);
  const unsigned* sbL[2] = { lb0 + soff, lb1 + soff };
  const unsigned* sbM[2] = { mr0 + soff, mr1 + soff };
  // producer store offset
  const size_t poff = SIDX(g, wsl, er, klo);

  for (int t = 0; t < TSTEPS; ++t) {
    // ---------- x projection from prefetched registers ----------
    f32x4 acc[4];
    #pragma unroll
    for (int nt = 0; nt < 4; ++nt) acc[nt] = (f32x4){0.f, 0.f, 0.f, 0.f};
    {
      s16x8 xhi, xlo;
      #pragma unroll
      for (int j = 0; j < 8; ++j) { short a, b; split_bf(xf[j], a, b); xhi[j] = a; xlo[j] = b; }
      #pragma unroll
      for (int nt = 0; nt < 4; ++nt) {
        acc[nt] = mfma16(xhi, wih_hi[nt], acc[nt]);
        acc[nt] = mfma16(xhi, wih_lo[nt], acc[nt]);
        acc[nt] = mfma16(xlo, wih_hi[nt], acc[nt]);
      }
    }
    // ---------- poll: sc0 sweeps on L2 buffer; every 8th miss, sc1 mirror sweep ----------
    const unsigned etag = (unsigned)((t >> 1) & 1);
    const unsigned* sb = sbL[t & 1];
    const unsigned* mb = sbM[t & 1];
    u32x4 sv0, sv1, sv2, sv3, sv4, sv5, sv6, sv7;
    {
      const u32x4 e4 = (u32x4){etag, etag, etag, etag};
      int miss = 0;
      for (;;) {
        // L2 fast path (sc0: bypass L1, served by shared per-XCD L2)
        asm volatile(
          "global_load_dwordx4 %0, %8, off sc0\n\t"
          "global_load_dwordx4 %1, %8, off offset:16 sc0\n\t"
          "global_load_dwordx4 %2, %8, off offset:128 sc0\n\t"
          "global_load_dwordx4 %3, %8, off offset:144 sc0\n\t"
          "global_load_dwordx4 %4, %8, off offset:256 sc0\n\t"
          "global_load_dwordx4 %5, %8, off offset:272 sc0\n\t"
          "global_load_dwordx4 %6, %8, off offset:384 sc0\n\t"
          "global_load_dwordx4 %7, %8, off offset:400 sc0\n\t"
          "s_waitcnt vmcnt(0)"
          : "=&v"(sv0), "=&v"(sv1), "=&v"(sv2), "=&v"(sv3),
            "=&v"(sv4), "=&v"(sv5), "=&v"(sv6), "=&v"(sv7)
          : "v"(sb) : "memory");
        {
          u32x4 b4 = (sv0 ^ e4) | (sv1 ^ e4) | (sv2 ^ e4) | (sv3 ^ e4)
                   | (sv4 ^ e4) | (sv5 ^ e4) | (sv6 ^ e4) | (sv7 ^ e4);
          unsigned bad = b4[0] | b4[1] | b4[2] | b4[3];
          if ((bad & 1u) == 0) break;
        }
        if (((++miss) & 7) == 0) {
          // IC truth path (liveness if producer landed cross-XCD)
          asm volatile(
            "global_load_dwordx4 %0, %8, off sc1\n\t"
            "global_load_dwordx4 %1, %8, off offset:16 sc1\n\t"
            "global_load_dwordx4 %2, %8, off offset:128 sc1\n\t"
            "global_load_dwordx4 %3, %8, off offset:144 sc1\n\t"
            "global_load_dwordx4 %4, %8, off offset:256 sc1\n\t"
            "global_load_dwordx4 %5, %8, off offset:272 sc1\n\t"
            "global_load_dwordx4 %6, %8, off offset:384 sc1\n\t"
            "global_load_dwordx4 %7, %8, off offset:400 sc1\n\t"
            "s_waitcnt vmcnt(0)"
            : "=&v"(sv0), "=&v"(sv1), "=&v"(sv2), "=&v"(sv3),
              "=&v"(sv4), "=&v"(sv5), "=&v"(sv6), "=&v"(sv7)
            : "v"(mb) : "memory");
          u32x4 b4 = (sv0 ^ e4) | (sv1 ^ e4) | (sv2 ^ e4) | (sv3 ^ e4)
                   | (sv4 ^ e4) | (sv5 ^ e4) | (sv6 ^ e4) | (sv7 ^ e4);
          unsigned bad = b4[0] | b4[1] | b4[2] | b4[3];
          if ((bad & 1u) == 0) break;
        }
      }
    }
    // ---------- prefetch x[t+1] (hides HBM latency under MFMA + epilogue) ----------
    {
      const int tn = (t + 1 < TSTEPS) ? (t + 1) : t;
      const float* xp = x + (size_t)tn * BATCH * NI + (size_t)(row0 + lr) * NI + iq0 + lq * 8;
      #pragma unroll
      for (int j = 0; j < 8; ++j) xf[j] = xp[j];
    }
    // ---------- recurrent MFMAs (unpack + 3-product bf16x2) ----------
    {
      unsigned sw[32];
      #pragma unroll
      for (int e = 0; e < 4; ++e) {
        sw[0  + e] = sv0[e]; sw[4  + e] = sv1[e];
        sw[8  + e] = sv2[e]; sw[12 + e] = sv3[e];
        sw[16 + e] = sv4[e]; sw[20 + e] = sv5[e];
        sw[24 + e] = sv6[e]; sw[28 + e] = sv7[e];
      }
      #pragma unroll
      for (int kb = 0; kb < 4; ++kb) {
        s16x8 shi, slo;
        #pragma unroll
        for (int j = 0; j < 8; ++j) {
          unsigned w = sw[kb * 8 + j];
          shi[j] = (short)(w >> 16);
          slo[j] = (short)(w & 0xffffu);
        }
        #pragma unroll
        for (int nt = 0; nt < 4; ++nt) {
          acc[nt] = mfma16(shi, whh_hi[nt][kb], acc[nt]);
          acc[nt] = mfma16(shi, whh_lo[nt][kb], acc[nt]);
          acc[nt] = mfma16(slo, whh_hi[nt][kb], acc[nt]);
        }
      }
    }
    // ---------- cross-wave K reduction (double-buffered -> ONE barrier/step) ----------
    const int rbi = t & 1;
    #pragma unroll
    for (int nt = 0; nt < 4; ++nt)
      #pragma unroll
      for (int r = 0; r < 4; ++r)
        red[rbi][wave][(lq * 4 + r) * 64 + nt * 16 + lr] = acc[nt][r];
    __syncthreads();
    // ---------- epilogue: reduce 8 waves, tanh, dual tagged store (fire, no drain) ----------
    {
      float s0 = bias0, s1 = bias1;
      #pragma unroll
      for (int w = 0; w < NWAVE; ++w) {
        float2 v = *(const float2*)&red[rbi][w][er * 64 + ec];
        s0 += v.x; s1 += v.y;
      }
      float t0 = fast_tanh(s0), t1 = fast_tanh(s1);
      const unsigned otag = (unsigned)(((t + 1) >> 1) & 1);
      unsigned short h0b = f2bf_rne(t0);
      unsigned       l0b = ((f2bf_rne(t0 - bf2f(h0b)) & 0xfffeu) | otag);
      unsigned short h1b = f2bf_rne(t1);
      unsigned       l1b = ((f2bf_rne(t1 - bf2f(h1b)) & 0xfffeu) | otag);
      ull pk = ((ull)(((unsigned)h1b << 16) | l1b) << 32)
             |  (ull)(((unsigned)h0b << 16) | l0b);
      unsigned* lbd = ((t + 1) & 1) ? lb1 : lb0;
      unsigned* mrd = ((t + 1) & 1) ? mr1 : mr0;
      ull* opL = (ull*)(lbd + poff);
      ull* opM = (ull*)(mrd + poff);
      // (a) plain store -> lands in this XCD's L2 (L1 write-through): fast path
      asm volatile("global_store_dwordx2 %0, %1, off" :: "v"(opL), "v"(pk) : "memory");
      // (b) sc1 store -> IC coherence point: liveness truth + readout source
      asm volatile("global_store_dwordx2 %0, %1, off sc1" :: "v"(opM), "v"(pk) : "memory");
    }
  }
}

__global__ __launch_bounds__(256)
void init_sp(unsigned* __restrict__ SP) {
  // regions: [0]=L2 buf0 (tag0 zeros), [1]=L2 buf1 (stale tag1),
  //          [2]=MIR buf0 (tag0 zeros), [3]=MIR buf1 (stale tag1)
  const size_t i = (size_t)blockIdx.x * 256 + threadIdx.x;
  SP[i] = (unsigned)((i >> 17) & 1);   // SPBUF = 2^17
}

__global__ __launch_bounds__(512)
void rnn_readout(const unsigned* __restrict__ SP,      // reads MIRROR buf0 (T even; sc1-visible)
                 const float* __restrict__ W_ro,       // [128][1024]
                 const float* __restrict__ b_ro,       // [128]
                 float* __restrict__ out)              // [128][128]
{
  __shared__ float srow[4][NH];
  const unsigned* MIR0 = SP + 2 * SPBUF;
  const int b0 = blockIdx.x * 4;
  for (int i = threadIdx.x; i < 4 * NH; i += 512) {
    const int b = b0 + (i >> 10);
    const int h = i & 1023;
    unsigned u = MIR0[SIDX(b >> 4, h >> 7, b & 15, h & 127)];
    srow[i >> 10][h] = bf2f((unsigned short)(u >> 16)) + bf2f((unsigned short)(u & 0xffffu));
  }
  __syncthreads();
  const int bb = threadIdx.x >> 7;
  const int o  = threadIdx.x & 127;
  const float* wr = W_ro + (size_t)o * NH;
  float s = 0.f;
  #pragma unroll 4
  for (int k = 0; k < NH; ++k) s += srow[bb][k] * wr[k];
  out[(size_t)(b0 + bb) * NO + o] = s + b_ro[o];
}

extern "C" void kernel_launch(void* const* d_in, const int* in_sizes, int n_in,
                              void* d_out, int out_size, void* d_ws, size_t ws_size,
                              hipStream_t stream) {
  (void)in_sizes; (void)n_in; (void)out_size; (void)ws_size;
  const float* x    = (const float*)d_in[0];
  const float* W_ih = (const float*)d_in[1];
  const float* W_hh = (const float*)d_in[2];
  const float* b_ih = (const float*)d_in[3];
  const float* b_hh = (const float*)d_in[4];
  const float* W_ro = (const float*)d_in[5];
  const float* b_ro = (const float*)d_in[6];
  float* out = (float*)d_out;

  unsigned* SP = (unsigned*)d_ws;   // [4][128][1024] u32 = 2 MB

  init_sp<<<(4 * BATCH * NH) / 256, 256, 0, stream>>>(SP);

  rnn_persistent<<<NBLK, NTHR, 0, stream>>>(x, W_ih, W_hh, b_ih, b_hh, SP);
  // T=512 even -> final state in buf0 (mirror copy, sc1-visible post-kernel)
  rnn_readout<<<BATCH / 4, 512, 0, stream>>>(SP, W_ro, b_ro, out);
}

// Round 6
// 1815.028 us; speedup vs baseline: 1.1721x; 1.1721x over previous
//
#include <hip/hip_runtime.h>
#include <hip/hip_bf16.h>
#include <stdint.h>

// Persistent-RNN, R10: SE(L2)-scoped exchange on BOTH sides + IC mirror liveness.
//  - 128 blocks x 512 threads (8 waves). 8 batch-groups x 16 col-blocks.
//  - Block (g,m): g = blockIdx&7 (group==XCD under round-robin dispatch -- PROVEN
//    by R8's FETCH_SIZE dedup), m = blockIdx>>3.
//  - R9 -> R10 (R9 forensics: sc0 polls NEVER saw fresh data -- FETCH fell to
//    x-only 74MB and all detections went through the rare mirror sweeps. Cause
//    is one/both of: plain store retained at CU level; sc0 load L1-served.
//    Counter history also shows WRITE_SIZE == full store volume every round:
//    the sc1 exchange round-trips HBM, hence the ~3.4us/step chain):
//      * Producer L2-path store now carries sc0 (SE scope: write-through past
//        L1 into this XCD's L2). Consumer keeps sc0 sweeps (SE scope: bypass
//        L1, served by the same L2). Both sides of the fast hop now scoped.
//      * Poll alternates 1:1 sc0(L2 buffer) / sc1(mirror) -- R8's proven
//        cadence as the liveness floor; if sc0-L2 works, detection happens at
//        L2 latency on the sc0 slots (sc0 store lands in L2 before the mirror
//        store reaches IC/HBM).
//      * Mirror (sc1 store + sc1 sweeps + readout source) is the correctness/
//        liveness truth: works cross-XCD, visible post-kernel.
//  - Tag protocol: u32 = (bf16hi<<16)|(bf16lo&~1|parity); all 32 tags must
//    equal (t>>1)&1. Stale lines at any cache level carry the OPPOSITE tag ->
//    tag-fail, never false-pass. Per-dword tags cover torn lines.
//  - WAR safety: as R5 -- any fresh word of producer B implies B passed its
//    step-(t-1) block barrier, implying all B's step-(t-1) state reads retired.

#define TSTEPS 512
#define BATCH  128
#define NI     256
#define NH     1024
#define NO     128
#define NBLK   128
#define NTHR   512
#define NWAVE  8
#define BG     16
#define COLS   64
#define SPBUF  ((size_t)BATCH * NH)          // u32s per state buffer (2^17)

typedef __attribute__((ext_vector_type(8))) short s16x8;
typedef __attribute__((ext_vector_type(4))) float f32x4;
typedef __attribute__((ext_vector_type(4))) unsigned u32x4;
typedef unsigned long long ull;

__device__ __forceinline__ unsigned short f2bf_rne(float f) {
  unsigned u = __builtin_bit_cast(unsigned, f);
  unsigned r = u + 0x7fffu + ((u >> 16) & 1u);
  return (unsigned short)(r >> 16);
}
__device__ __forceinline__ float bf2f(unsigned short h) {
  unsigned u = ((unsigned)h) << 16;
  return __builtin_bit_cast(float, u);
}
__device__ __forceinline__ void split_bf(float v, short &hi, short &lo) {
  unsigned short h = f2bf_rne(v);
  hi = (short)h;
  lo = (short)f2bf_rne(v - bf2f(h));
}
__device__ __forceinline__ f32x4 mfma16(s16x8 a, s16x8 b, f32x4 c) {
  return __builtin_amdgcn_mfma_f32_16x16x32_bf16(a, b, c, 0, 0, 0);
}
__device__ __forceinline__ float fast_tanh(float a) {
  float cl = fminf(fmaxf(a, -15.f), 15.f);
  float e  = __expf(2.f * cl);
  return (e - 1.f) / (e + 1.f);
}

// state u32 index: [g 0..8)[w 0..8)[r 0..16)[k_local 0..128)
//   global K = w*128 + k_local ; batch row = g*16 + r
#define SIDX(g, w, r, k) ((((size_t)(g) * NWAVE + (w)) * BG + (r)) * 128 + (k))

__global__ __launch_bounds__(NTHR, 2)
void rnn_persistent(const float* __restrict__ x,
                    const float* __restrict__ W_ih,
                    const float* __restrict__ W_hh,
                    const float* __restrict__ b_ih,
                    const float* __restrict__ b_hh,
                    unsigned*    __restrict__ SP)    // [4][128][1024]: L2buf0,L2buf1,MIR0,MIR1
{
  const int tid  = threadIdx.x;
  const int wave = tid >> 6;
  const int lane = tid & 63;
  const int lr   = lane & 15;
  const int lq   = lane >> 4;
  const int g    = blockIdx.x & 7;     // group == chain == XCD (round-robin, proven R8)
  const int m    = blockIdx.x >> 3;    // 16 col-blocks per group
  const int row0 = g * BG;
  const int h0   = m * COLS;
  const int kq0  = wave * 128;         // this wave's hidden-K slice
  const int iq0  = wave * 32;          // this wave's input-K slice

  __shared__ float red[2][NWAVE][1024];

  // ---- persistent W_hh B-fragments: [n-tile 0..3][kb 0..3], hi/lo ----
  s16x8 whh_hi[4][4], whh_lo[4][4];
  #pragma unroll
  for (int nt = 0; nt < 4; ++nt) {
    const int h = h0 + nt * 16 + lr;
    #pragma unroll
    for (int kb = 0; kb < 4; ++kb) {
      const float* p = W_hh + (size_t)h * NH + kq0 + kb * 32 + lq * 8;
      s16x8 hi, lo;
      #pragma unroll
      for (int j = 0; j < 8; ++j) { short a, b; split_bf(p[j], a, b); hi[j] = a; lo[j] = b; }
      whh_hi[nt][kb] = hi; whh_lo[nt][kb] = lo;
    }
  }
  // ---- persistent W_ih B-fragments: [n-tile 0..3], single 32-wide kb ----
  s16x8 wih_hi[4], wih_lo[4];
  #pragma unroll
  for (int nt = 0; nt < 4; ++nt) {
    const int h = h0 + nt * 16 + lr;
    const float* p = W_ih + (size_t)h * NI + iq0 + lq * 8;
    s16x8 hi, lo;
    #pragma unroll
    for (int j = 0; j < 8; ++j) { short a, b; split_bf(p[j], a, b); hi[j] = a; lo[j] = b; }
    wih_hi[nt] = hi; wih_lo[nt] = lo;
  }

  // epilogue ownership: thread -> row tid>>5, cols 2*(tid&31), +1
  const int er = tid >> 5;
  const int ec = (tid & 31) * 2;
  const float bias0 = b_ih[h0 + ec]     + b_hh[h0 + ec];
  const float bias1 = b_ih[h0 + ec + 1] + b_hh[h0 + ec + 1];
  const int wsl = m >> 1;              // wave-slice this block's cols land in
  const int klo = (m & 1) * 64 + ec;   // k_local of this thread's pair

  unsigned* lb0 = SP;                  // L2-scope double buffer
  unsigned* lb1 = SP + SPBUF;
  unsigned* mr0 = SP + 2 * SPBUF;      // IC mirror double buffer
  unsigned* mr1 = SP + 3 * SPBUF;

  // x prefetch registers (step 0)
  float xf[8];
  {
    const float* xp = x + (size_t)(row0 + lr) * NI + iq0 + lq * 8;
    #pragma unroll
    for (int j = 0; j < 8; ++j) xf[j] = xp[j];
  }

  // consumer poll bases: this wave's contiguous slice, per-lane fragment offset
  const size_t soff = SIDX(g, wave, lr, lq * 8);
  const unsigned* sbL[2] = { lb0 + soff, lb1 + soff };
  const unsigned* sbM[2] = { mr0 + soff, mr1 + soff };
  // producer store offset
  const size_t poff = SIDX(g, wsl, er, klo);

  for (int t = 0; t < TSTEPS; ++t) {
    // ---------- x projection from prefetched registers ----------
    f32x4 acc[4];
    #pragma unroll
    for (int nt = 0; nt < 4; ++nt) acc[nt] = (f32x4){0.f, 0.f, 0.f, 0.f};
    {
      s16x8 xhi, xlo;
      #pragma unroll
      for (int j = 0; j < 8; ++j) { short a, b; split_bf(xf[j], a, b); xhi[j] = a; xlo[j] = b; }
      #pragma unroll
      for (int nt = 0; nt < 4; ++nt) {
        acc[nt] = mfma16(xhi, wih_hi[nt], acc[nt]);
        acc[nt] = mfma16(xhi, wih_lo[nt], acc[nt]);
        acc[nt] = mfma16(xlo, wih_hi[nt], acc[nt]);
      }
    }
    // ---------- poll: alternate sc0 sweep (L2 fast path) / sc1 sweep (IC truth) ----------
    const unsigned etag = (unsigned)((t >> 1) & 1);
    const unsigned* sb = sbL[t & 1];
    const unsigned* mb = sbM[t & 1];
    u32x4 sv0, sv1, sv2, sv3, sv4, sv5, sv6, sv7;
    {
      const u32x4 e4 = (u32x4){etag, etag, etag, etag};
      for (;;) {
        // L2 fast path: sc0 (SE scope -> bypass L1, served by this XCD's L2)
        asm volatile(
          "global_load_dwordx4 %0, %8, off sc0\n\t"
          "global_load_dwordx4 %1, %8, off offset:16 sc0\n\t"
          "global_load_dwordx4 %2, %8, off offset:128 sc0\n\t"
          "global_load_dwordx4 %3, %8, off offset:144 sc0\n\t"
          "global_load_dwordx4 %4, %8, off offset:256 sc0\n\t"
          "global_load_dwordx4 %5, %8, off offset:272 sc0\n\t"
          "global_load_dwordx4 %6, %8, off offset:384 sc0\n\t"
          "global_load_dwordx4 %7, %8, off offset:400 sc0\n\t"
          "s_waitcnt vmcnt(0)"
          : "=&v"(sv0), "=&v"(sv1), "=&v"(sv2), "=&v"(sv3),
            "=&v"(sv4), "=&v"(sv5), "=&v"(sv6), "=&v"(sv7)
          : "v"(sb) : "memory");
        {
          u32x4 b4 = (sv0 ^ e4) | (sv1 ^ e4) | (sv2 ^ e4) | (sv3 ^ e4)
                   | (sv4 ^ e4) | (sv5 ^ e4) | (sv6 ^ e4) | (sv7 ^ e4);
          unsigned bad = b4[0] | b4[1] | b4[2] | b4[3];
          if ((bad & 1u) == 0) break;
        }
        // IC truth path (liveness regardless of placement/scope semantics)
        asm volatile(
          "global_load_dwordx4 %0, %8, off sc1\n\t"
          "global_load_dwordx4 %1, %8, off offset:16 sc1\n\t"
          "global_load_dwordx4 %2, %8, off offset:128 sc1\n\t"
          "global_load_dwordx4 %3, %8, off offset:144 sc1\n\t"
          "global_load_dwordx4 %4, %8, off offset:256 sc1\n\t"
          "global_load_dwordx4 %5, %8, off offset:272 sc1\n\t"
          "global_load_dwordx4 %6, %8, off offset:384 sc1\n\t"
          "global_load_dwordx4 %7, %8, off offset:400 sc1\n\t"
          "s_waitcnt vmcnt(0)"
          : "=&v"(sv0), "=&v"(sv1), "=&v"(sv2), "=&v"(sv3),
            "=&v"(sv4), "=&v"(sv5), "=&v"(sv6), "=&v"(sv7)
          : "v"(mb) : "memory");
        {
          u32x4 b4 = (sv0 ^ e4) | (sv1 ^ e4) | (sv2 ^ e4) | (sv3 ^ e4)
                   | (sv4 ^ e4) | (sv5 ^ e4) | (sv6 ^ e4) | (sv7 ^ e4);
          unsigned bad = b4[0] | b4[1] | b4[2] | b4[3];
          if ((bad & 1u) == 0) break;
        }
      }
    }
    // ---------- prefetch x[t+1] (hides HBM latency under MFMA + epilogue) ----------
    {
      const int tn = (t + 1 < TSTEPS) ? (t + 1) : t;
      const float* xp = x + (size_t)tn * BATCH * NI + (size_t)(row0 + lr) * NI + iq0 + lq * 8;
      #pragma unroll
      for (int j = 0; j < 8; ++j) xf[j] = xp[j];
    }
    // ---------- recurrent MFMAs (unpack + 3-product bf16x2) ----------
    {
      unsigned sw[32];
      #pragma unroll
      for (int e = 0; e < 4; ++e) {
        sw[0  + e] = sv0[e]; sw[4  + e] = sv1[e];
        sw[8  + e] = sv2[e]; sw[12 + e] = sv3[e];
        sw[16 + e] = sv4[e]; sw[20 + e] = sv5[e];
        sw[24 + e] = sv6[e]; sw[28 + e] = sv7[e];
      }
      #pragma unroll
      for (int kb = 0; kb < 4; ++kb) {
        s16x8 shi, slo;
        #pragma unroll
        for (int j = 0; j < 8; ++j) {
          unsigned w = sw[kb * 8 + j];
          shi[j] = (short)(w >> 16);
          slo[j] = (short)(w & 0xffffu);
        }
        #pragma unroll
        for (int nt = 0; nt < 4; ++nt) {
          acc[nt] = mfma16(shi, whh_hi[nt][kb], acc[nt]);
          acc[nt] = mfma16(shi, whh_lo[nt][kb], acc[nt]);
          acc[nt] = mfma16(slo, whh_hi[nt][kb], acc[nt]);
        }
      }
    }
    // ---------- cross-wave K reduction (double-buffered -> ONE barrier/step) ----------
    const int rbi = t & 1;
    #pragma unroll
    for (int nt = 0; nt < 4; ++nt)
      #pragma unroll
      for (int r = 0; r < 4; ++r)
        red[rbi][wave][(lq * 4 + r) * 64 + nt * 16 + lr] = acc[nt][r];
    __syncthreads();
    // ---------- epilogue: reduce 8 waves, tanh, dual tagged store (fire, no drain) ----------
    {
      float s0 = bias0, s1 = bias1;
      #pragma unroll
      for (int w = 0; w < NWAVE; ++w) {
        float2 v = *(const float2*)&red[rbi][w][er * 64 + ec];
        s0 += v.x; s1 += v.y;
      }
      float t0 = fast_tanh(s0), t1 = fast_tanh(s1);
      const unsigned otag = (unsigned)(((t + 1) >> 1) & 1);
      unsigned short h0b = f2bf_rne(t0);
      unsigned       l0b = ((f2bf_rne(t0 - bf2f(h0b)) & 0xfffeu) | otag);
      unsigned short h1b = f2bf_rne(t1);
      unsigned       l1b = ((f2bf_rne(t1 - bf2f(h1b)) & 0xfffeu) | otag);
      ull pk = ((ull)(((unsigned)h1b << 16) | l1b) << 32)
             |  (ull)(((unsigned)h0b << 16) | l0b);
      unsigned* lbd = ((t + 1) & 1) ? lb1 : lb0;
      unsigned* mrd = ((t + 1) & 1) ? mr1 : mr0;
      ull* opL = (ull*)(lbd + poff);
      ull* opM = (ull*)(mrd + poff);
      // (a) sc0 store -> SE scope: write-through past L1 into this XCD's L2
      asm volatile("global_store_dwordx2 %0, %1, off sc0" :: "v"(opL), "v"(pk) : "memory");
      // (b) sc1 store -> IC/HBM coherence point: liveness truth + readout source
      asm volatile("global_store_dwordx2 %0, %1, off sc1" :: "v"(opM), "v"(pk) : "memory");
    }
  }
}

__global__ __launch_bounds__(256)
void init_sp(unsigned* __restrict__ SP) {
  // regions: [0]=L2 buf0 (tag0 zeros), [1]=L2 buf1 (stale tag1),
  //          [2]=MIR buf0 (tag0 zeros), [3]=MIR buf1 (stale tag1)
  const size_t i = (size_t)blockIdx.x * 256 + threadIdx.x;
  SP[i] = (unsigned)((i >> 17) & 1);   // SPBUF = 2^17
}

__global__ __launch_bounds__(512)
void rnn_readout(const unsigned* __restrict__ SP,      // reads MIRROR buf0 (T even; sc1-visible)
                 const float* __restrict__ W_ro,       // [128][1024]
                 const float* __restrict__ b_ro,       // [128]
                 float* __restrict__ out)              // [128][128]
{
  __shared__ float srow[4][NH];
  const unsigned* MIR0 = SP + 2 * SPBUF;
  const int b0 = blockIdx.x * 4;
  for (int i = threadIdx.x; i < 4 * NH; i += 512) {
    const int b = b0 + (i >> 10);
    const int h = i & 1023;
    unsigned u = MIR0[SIDX(b >> 4, h >> 7, b & 15, h & 127)];
    srow[i >> 10][h] = bf2f((unsigned short)(u >> 16)) + bf2f((unsigned short)(u & 0xffffu));
  }
  __syncthreads();
  const int bb = threadIdx.x >> 7;
  const int o  = threadIdx.x & 127;
  const float* wr = W_ro + (size_t)o * NH;
  float s = 0.f;
  #pragma unroll 4
  for (int k = 0; k < NH; ++k) s += srow[bb][k] * wr[k];
  out[(size_t)(b0 + bb) * NO + o] = s + b_ro[o];
}

extern "C" void kernel_launch(void* const* d_in, const int* in_sizes, int n_in,
                              void* d_out, int out_size, void* d_ws, size_t ws_size,
                              hipStream_t stream) {
  (void)in_sizes; (void)n_in; (void)out_size; (void)ws_size;
  const float* x    = (const float*)d_in[0];
  const float* W_ih = (const float*)d_in[1];
  const float* W_hh = (const float*)d_in[2];
  const float* b_ih = (const float*)d_in[3];
  const float* b_hh = (const float*)d_in[4];
  const float* W_ro = (const float*)d_in[5];
  const float* b_ro = (const float*)d_in[6];
  float* out = (float*)d_out;

  unsigned* SP = (unsigned*)d_ws;   // [4][128][1024] u32 = 2 MB

  init_sp<<<(4 * BATCH * NH) / 256, 256, 0, stream>>>(SP);

  rnn_persistent<<<NBLK, NTHR, 0, stream>>>(x, W_ih, W_hh, b_ih, b_hh, SP);
  // T=512 even -> final state in buf0 (mirror copy, sc1-visible post-kernel)
  rnn_readout<<<BATCH / 4, 512, 0, stream>>>(SP, W_ro, b_ro, out);
}